// Round 1
// baseline (174.663 us; speedup 1.0000x reference)
//
#include <hip/hip_runtime.h>
#include <cstdint>
#include <cstddef>

#define NUM_HEADS 16
#define HEAD_DIM  64
#define WINDOW    512
#define D_MODEL   1024
#define BATCH     2
#define SEQ       2048
#define MTOT      (BATCH*SEQ)   // 4096
#define NQKV      (3*D_MODEL)   // 3072

typedef short bf16x8 __attribute__((ext_vector_type(8)));
typedef float f32x4  __attribute__((ext_vector_type(4)));

__device__ __forceinline__ f32x4 mfma16(bf16x8 a, bf16x8 b, f32x4 c) {
  return __builtin_amdgcn_mfma_f32_16x16x32_bf16(a, b, c, 0, 0, 0);
}

__device__ __forceinline__ unsigned short f2bf(float f) {
  unsigned int u = __float_as_uint(f);
  u += 0x7fffu + ((u >> 16) & 1u);
  return (unsigned short)(u >> 16);
}
__device__ __forceinline__ float bf2f(unsigned short b) {
  return __uint_as_float(((unsigned int)b) << 16);
}

// async global->LDS, 16B/lane; LDS dest = wave-uniform base + lane*16 (m104).
__device__ __forceinline__ void gld16(const unsigned short* g, unsigned short* l) {
  __builtin_amdgcn_global_load_lds(
      (const __attribute__((address_space(1))) unsigned int*)g,
      (__attribute__((address_space(3))) unsigned int*)l, 16, 0, 0);
}

// ---------------- fused prep: x->bf16 | qkv_w^T->bf16 | out_w^T->bf16 ----------------
__global__ __launch_bounds__(256) void prep_kernel(const float* __restrict__ x,
                                                   const float* __restrict__ qkv_w,
                                                   const float* __restrict__ out_w,
                                                   unsigned short* __restrict__ Xb,
                                                   unsigned short* __restrict__ Wq,
                                                   unsigned short* __restrict__ Wo) {
  __shared__ float tile[32][33];
  const int bid = blockIdx.x, t = threadIdx.x;
  if (bid < 4096) {
    int i = (bid * 256 + t) * 4;
    float4 v = *(const float4*)(x + i);
    ushort4 o;
    o.x = f2bf(v.x); o.y = f2bf(v.y); o.z = f2bf(v.z); o.w = f2bf(v.w);
    *(ushort4*)(Xb + i) = o;
    return;
  }
  const float* in; unsigned short* out; int R, C, bx, by;
  if (bid < 7168) { int b2 = bid - 4096; in = qkv_w; out = Wq; R = D_MODEL; C = NQKV; bx = b2 % 96; by = b2 / 96; }
  else            { int b2 = bid - 7168; in = out_w; out = Wo; R = D_MODEL; C = D_MODEL; bx = b2 & 31; by = b2 >> 5; }
  int tx = t & 31, ty = t >> 5;            // (32, 8)
  int c0 = bx * 32, r0 = by * 32;
#pragma unroll
  for (int i = 0; i < 32; i += 8)
    tile[ty + i][tx] = in[(size_t)(r0 + ty + i) * C + c0 + tx];
  __syncthreads();
#pragma unroll
  for (int i = 0; i < 32; i += 8)
    out[(size_t)(c0 + ty + i) * R + r0 + tx] = f2bf(tile[tx][ty + i]);
}

// ---------------- 512-thread 3-stage pipelined GEMM mainloop, XOR-swizzled LDS -----------
// (kept for out_gemm: grid there is 256 blocks / 1 per CU; see out_gemm_kernel)
template<bool SWAP, int K>
__device__ __forceinline__ void gemm_mainloop512(const unsigned short* __restrict__ A,
                                                 const unsigned short* __restrict__ Bt,
                                                 int m0, int n0,
                                                 unsigned short* sA, unsigned short* sB,
                                                 f32x4 (&acc)[2][4]) {
  const int t = threadIdx.x;
  const int lane = t & 63, wave = t >> 6;
  const int wr = wave >> 1, wc = wave & 1;   // 4x2 wave grid
  const int lhi = lane >> 4, llo = lane & 15;
  f32x4 zero = {0.f, 0.f, 0.f, 0.f};
#pragma unroll
  for (int i = 0; i < 2; ++i)
#pragma unroll
    for (int j = 0; j < 4; ++j) acc[i][j] = zero;

  const int cswz = (((t & 3) ^ ((t >> 3) & 3)) << 3);   // swizzled k-chunk for staging
  const unsigned short* gA = A  + (size_t)(m0 + (t >> 2)) * K + cswz;
  const unsigned short* gB = Bt + (size_t)(n0 + (t >> 2)) * K + cswz;
  const int ldsT = t * 8;
  const int rsw  = (lhi ^ ((llo >> 1) & 3)) * 8;        // swizzled chunk for frag reads
  const int aoff = (wr * 32 + llo) * 32 + rsw;
  const int boff = (wc * 64 + llo) * 32 + rsw;
  constexpr int nIter = K / 32;

  auto stage = [&](int s) {
    unsigned short* dA = sA + (s % 3) * 4096;
    unsigned short* dB = sB + (s % 3) * 4096;
    gld16(gA + s * 32, dA + ldsT);
    gld16(gB + s * 32, dB + ldsT);
  };

  stage(0);
  stage(1);
#pragma unroll
  for (int it = 0; it < nIter; ++it) {
    // wait tile `it` (2 oldest loads); keep tile `it+1` (2 newest) in flight
    if (it + 1 < nIter) asm volatile("s_waitcnt vmcnt(2)\n\ts_barrier" ::: "memory");
    else                asm volatile("s_waitcnt vmcnt(0)\n\ts_barrier" ::: "memory");
    if (it + 2 < nIter) stage(it + 2);
    const unsigned short* cA = sA + (it % 3) * 4096;
    const unsigned short* cB = sB + (it % 3) * 4096;
    bf16x8 af[2], bfr[4];
#pragma unroll
    for (int i = 0; i < 2; ++i) af[i]  = *(const bf16x8*)(cA + aoff + i * 512);
#pragma unroll
    for (int j = 0; j < 4; ++j)  bfr[j] = *(const bf16x8*)(cB + boff + j * 512);
#pragma unroll
    for (int i = 0; i < 2; ++i)
#pragma unroll
      for (int j = 0; j < 4; ++j)
        acc[i][j] = SWAP ? mfma16(bfr[j], af[i], acc[i][j])
                         : mfma16(af[i], bfr[j], acc[i][j]);
  }
}

// ---------------- 256x256-tile phase-split mainloop (T3+T4+T5), 4-slot LDS ring ----------
// 8 waves in 2(M)x4(N): wave tile 128x64 -> per wave per K-tile(32): A read once
// (8 ds_read_b128), B read twice (8) => block LDS traffic 128KB/K-tile vs MFMA
// 8x32x4.85 = 1240cy: MFMA-bound (the 128x128 loop above is LDS-bound at 3x re-read).
// LDS: 4 ring slots x (A 16KB + B 16KB) = 128KB -> 1 block/CU, 2 waves/SIMD.
// Staging: tile t+2 issued during tile t's two phases (slot (t+2)&3 last read at
// tile t-2, >=2 barriers ago => write-safe). Boundary wait vmcnt(4) keeps the
// newest tile's 4 loads in flight across the barrier (never drains to 0 until
// the last tile) — the T4 counted-vmcnt discipline.
template<bool SWAP>
__device__ __forceinline__ void gemm_mainloop_256sq(const unsigned short* __restrict__ A,
                                                    const unsigned short* __restrict__ Bt,
                                                    int m0, int n0,
                                                    unsigned short* sA, unsigned short* sB,
                                                    f32x4 (&acc)[8][4]) {
  constexpr int K  = D_MODEL;      // 1024
  constexpr int nT = K / 32;       // 32 K-tiles
  const int t = threadIdx.x;
  const int lane = t & 63, wave = t >> 6;
  const int wr = wave >> 2, wc = wave & 3;      // 2(M) x 4(N) wave grid
  const int lhi = lane >> 4, llo = lane & 15;
  f32x4 zero = {0.f, 0.f, 0.f, 0.f};
#pragma unroll
  for (int i = 0; i < 8; ++i)
#pragma unroll
    for (int j = 0; j < 4; ++j) acc[i][j] = zero;

  // staging: thread t covers (row = u*128 + (t>>2), chunk = t&3) of a 256x32 tile;
  // swizzle key (row>>1)&3 == (t>>3)&3 for both units (u*128 keeps bit1 clear).
  const int cswz = (((t & 3) ^ ((t >> 3) & 3)) << 3);
  const unsigned short* gA0 = A  + (size_t)(m0 + (t >> 2)) * K + cswz;
  const unsigned short* gA1 = gA0 + (size_t)128 * K;
  const unsigned short* gB0 = Bt + (size_t)(n0 + (t >> 2)) * K + cswz;
  const unsigned short* gB1 = gB0 + (size_t)128 * K;
  const int ldsT0 = t * 8, ldsT1 = 4096 + t * 8;

  // frag reads: row = (wr*128 + mi*16 + llo), swizzle key (row>>1)&3 == (llo>>1)&3
  const int rsw  = (lhi ^ ((llo >> 1) & 3)) * 8;
  const int aoff = (wr * 128 + llo) * 32 + rsw;   // + mi*512
  const int boff = (wc * 64  + llo) * 32 + rsw;   // + nj*512

  auto stageA = [&](int tile) {
    unsigned short* d = sA + (tile & 3) * 8192;
    gld16(gA0 + tile * 32, d + ldsT0);
    gld16(gA1 + tile * 32, d + ldsT1);
  };
  auto stageB = [&](int tile) {
    unsigned short* d = sB + (tile & 3) * 8192;
    gld16(gB0 + tile * 32, d + ldsT0);
    gld16(gB1 + tile * 32, d + ldsT1);
  };

  auto compute = [&](int tile, bool prefetch) {
    const unsigned short* cA = sA + (tile & 3) * 8192;
    const unsigned short* cB = sB + (tile & 3) * 8192;
#pragma unroll
    for (int mh = 0; mh < 2; ++mh) {            // phase = half of the M frag grid
      if (prefetch) { if (mh == 0) stageA(tile + 2); else stageB(tile + 2); }
      bf16x8 af[4], bfr[4];
#pragma unroll
      for (int i = 0; i < 4; ++i) af[i]  = *(const bf16x8*)(cA + aoff + (mh * 4 + i) * 512);
#pragma unroll
      for (int j = 0; j < 4; ++j) bfr[j] = *(const bf16x8*)(cB + boff + j * 512);
      __builtin_amdgcn_s_setprio(1);
#pragma unroll
      for (int i = 0; i < 4; ++i)
#pragma unroll
        for (int j = 0; j < 4; ++j)
          acc[mh * 4 + i][j] = SWAP ? mfma16(bfr[j], af[i], acc[mh * 4 + i][j])
                                    : mfma16(af[i], bfr[j], acc[mh * 4 + i][j]);
      __builtin_amdgcn_s_setprio(0);
      if (mh == 0) __builtin_amdgcn_s_barrier();  // phase boundary (schedule lockstep)
    }
  };

  stageA(0); stageB(0); stageA(1); stageB(1);     // 8 loads in flight

  for (int tile = 0; tile < nT - 2; ++tile) {
    // tile's 4 loads are >=8-old => landed after vmcnt(4); newest 4 (tile+1) stay in flight
    asm volatile("s_waitcnt vmcnt(4)\n\ts_barrier" ::: "memory");
    compute(tile, true);
  }
  asm volatile("s_waitcnt vmcnt(4)\n\ts_barrier" ::: "memory");
  compute(nT - 2, false);
  asm volatile("s_waitcnt vmcnt(0)\n\ts_barrier" ::: "memory");
  compute(nT - 1, false);
}

// ---------------- QKV projection GEMM (256x256 tile, 512 threads) ------------------------
// n0 < 2048: Q/K, normal orientation, coalesced (bh,s,d) stores.
// n0 >= 2048: V, transposed accumulator, DIRECT V^T (bh,d,s) stores.
// 256-tiles never straddle the Q/K/V boundaries (1024 & 2048 are multiples of 256).
__global__ __launch_bounds__(512, 2) void qkv_gemm_kernel(const unsigned short* __restrict__ Xb,
                                                          const unsigned short* __restrict__ Wt,
                                                          const float* __restrict__ bias,
                                                          unsigned short* __restrict__ Qw,
                                                          unsigned short* __restrict__ Kw,
                                                          unsigned short* __restrict__ Vtw) {
  __shared__ __align__(16) unsigned short sA[4][256 * 32];   // 64 KB
  __shared__ __align__(16) unsigned short sB[4][256 * 32];   // 64 KB
  f32x4 acc[8][4];
  const int m0 = blockIdx.y * 256, n0 = blockIdx.x * 256;
  const int t = threadIdx.x, lane = t & 63, wave = t >> 6;
  const int wr = wave >> 2, wc = wave & 3, lhi = lane >> 4, llo = lane & 15;

  if (n0 < 2048) {
    gemm_mainloop_256sq<false>(Xb, Wt, m0, n0, sA[0], sB[0], acc);
    const int c = n0 >> 10;     // block-uniform: Q or K
    unsigned short* __restrict__ Dst = (c == 0) ? Qw : Kw;
    const float qs = (c == 0) ? 0.125f : 1.0f;
#pragma unroll
    for (int mi = 0; mi < 8; ++mi) {
#pragma unroll
      for (int nj = 0; nj < 4; ++nj) {
        int n = n0 + wc * 64 + nj * 16 + llo;
        float bv = bias[n];
        int h = (n >> 6) & 15, d = n & 63;
#pragma unroll
        for (int r = 0; r < 4; ++r) {
          int m = m0 + wr * 128 + mi * 16 + lhi * 4 + r;
          int b = m >> 11, s = m & 2047;
          int bh = b * 16 + h;
          Dst[((size_t)(bh * 2048 + s)) * 64 + d] = f2bf((acc[mi][nj][r] + bv) * qs);
        }
      }
    }
  } else {
    gemm_mainloop_256sq<true>(Xb, Wt, m0, n0, sA[0], sB[0], acc);
#pragma unroll
    for (int mi = 0; mi < 8; ++mi) {
      int m = m0 + wr * 128 + mi * 16 + llo;   // s-dim (col of C^T)
      int b = m >> 11, s = m & 2047;
#pragma unroll
      for (int nj = 0; nj < 4; ++nj) {
        int nb = n0 + wc * 64 + nj * 16 + lhi * 4;   // d-base (row of C^T), 4-aligned
        float4 bv = *(const float4*)(bias + nb);
        int h = (nb >> 6) & 15, dbase = nb & 63;
        int bh = b * 16 + h;
        float bvr[4] = {bv.x, bv.y, bv.z, bv.w};
#pragma unroll
        for (int r = 0; r < 4; ++r)
          Vtw[(size_t)(bh * 64 + dbase + r) * 2048 + s] = f2bf(acc[mi][nj][r] + bvr[r]);
      }
    }
  }
}

// ---------------- flash sliding-window attention (S^T, 512 threads, 3-stage K/V) ---------
__global__ __launch_bounds__(512) void attn_kernel(const unsigned short* __restrict__ Qw,
                                                   const unsigned short* __restrict__ Kw,
                                                   const unsigned short* __restrict__ Vtw,
                                                   unsigned short* __restrict__ AO) {
  __shared__ __align__(16) unsigned short sK[3][64 * 64];  // (key,d), XOR-swizzled chunks
  __shared__ __align__(16) unsigned short sV[3][64 * 64];  // (d,key), XOR-swizzled chunks
  __shared__ __align__(16) unsigned short sP[8][16 * 72];  // per-wave P (query,key), pad 72
  const int t = threadIdx.x, lane = t & 63, wave = t >> 6;  // wave 0..7
  const int lhi = lane >> 4, llo = lane & 15;
  const int bh = blockIdx.x;                 // bh%8 -> XCD; q-tiles of bh share L2
  const int q0 = (15 - blockIdx.y) << 7;     // heaviest q-tiles dispatch first
  const unsigned short* Qb = Qw  + (size_t)bh * 2048 * 64;
  const unsigned short* Kb = Kw  + (size_t)bh * 2048 * 64;
  const unsigned short* Vb = Vtw + (size_t)bh * 64 * 2048;

  const int qw = q0 + wave * 16;             // this wave's query base
  const int qrow = qw + llo;                 // this lane's query (column of S^T)
  bf16x8 qf0 = *(const bf16x8*)(Qb + (size_t)qrow * 64 + lhi * 8);
  bf16x8 qf1 = *(const bf16x8*)(Qb + (size_t)qrow * 64 + 32 + lhi * 8);

  const int srow = t >> 3;                   // 512 threads cover a full 64x64 bf16 tile
  const int scol = ((t & 7) ^ (srow & 7)) * 8;   // XOR-swizzled staging chunk
  const int cpos  = (lhi ^ (llo & 7)) * 8;       // swizzled chunk for frag reads
  const int cposx = cpos ^ 32;                   // chunk c^4

  float m_i = -1e30f, l_i = 0.f;
  f32x4 o[4];
  f32x4 zero = {0.f, 0.f, 0.f, 0.f};
#pragma unroll
  for (int td = 0; td < 4; ++td) o[td] = zero;

  const int kt_lo = (q0 > 511) ? ((q0 - 511) >> 6) : 0;
  const int kt_hi = (q0 + 127) >> 6;         // every block has >= 2 k-tiles

  auto stageKV = [&](int j) {
    const int k0 = j << 6;
    unsigned short* dK = sK[j % 3];
    unsigned short* dV = sV[j % 3];
    gld16(Kb + (size_t)(k0 + srow) * 64 + scol, dK + t * 8);
    gld16(Vb + (size_t)srow * 2048 + k0 + scol, dV + t * 8);
  };

  stageKV(kt_lo);
  stageKV(kt_lo + 1);

  for (int kt = kt_lo; kt <= kt_hi; ++kt) {
    // wait for tile kt (2 oldest); keep tile kt+1 (2 newest) in flight across barrier
    if (kt < kt_hi) asm volatile("s_waitcnt vmcnt(2)\n\ts_barrier" ::: "memory");
    else            asm volatile("s_waitcnt vmcnt(0)\n\ts_barrier" ::: "memory");
    if (kt + 2 <= kt_hi) stageKV(kt + 2);
    const int k0 = kt << 6;
    // per-wave uniform skip: wave queries qw..qw+15, window union [qw-511, qw+15]
    if (k0 > qw + 15 || k0 + 63 < qw - (WINDOW - 1)) continue;  // no barrier inside

    const unsigned short* bK = sK[kt % 3];
    const unsigned short* bV = sV[kt % 3];

    // S^T tiles: row = key (tk*16 + lhi*4 + r), col = query (llo)
    f32x4 st[4];
#pragma unroll
    for (int tk = 0; tk < 4; ++tk) {
      const unsigned short* kr = bK + (tk * 16 + llo) * 64;
      bf16x8 kf0 = *(const bf16x8*)(kr + cpos);
      bf16x8 kf1 = *(const bf16x8*)(kr + cposx);
      f32x4 z = zero;
      z = mfma16(kf0, qf0, z);
      z = mfma16(kf1, qf1, z);
      st[tk] = z;
    }

    // wave-uniform interior fast path: all 16 keysx queries valid -> skip masking
    const bool interior = (k0 >= qw - (WINDOW - 1 - 15)) && (k0 + 63 <= qw);
    const int kb = k0 + lhi * 4;
    float mx = -1e30f;
    if (interior) {
#pragma unroll
      for (int tk = 0; tk < 4; ++tk)
#pragma unroll
        for (int r = 0; r < 4; ++r) mx = fmaxf(mx, st[tk][r]);
    } else {
#pragma unroll
      for (int tk = 0; tk < 4; ++tk)
#pragma unroll
        for (int r = 0; r < 4; ++r) {
          int key = kb + tk * 16 + r;
          bool ok = (key <= qrow) && (qrow - key < WINDOW);
          float s = ok ? st[tk][r] : -1e30f;
          st[tk][r] = s;
          mx = fmaxf(mx, s);
        }
    }
    mx = fmaxf(mx, __shfl_xor(mx, 16));
    mx = fmaxf(mx, __shfl_xor(mx, 32));
    float mn = fmaxf(m_i, mx);
    float a  = __expf(m_i - mn);  // fully-masked tile garbage wiped by a=0 on next real tile
    float rs = 0.f;
    unsigned short* pw = &sP[wave][llo * 72];
#pragma unroll
    for (int tk = 0; tk < 4; ++tk) {
      ushort4 pb;
      pb.x = f2bf(__expf(st[tk][0] - mn));
      pb.y = f2bf(__expf(st[tk][1] - mn));
      pb.z = f2bf(__expf(st[tk][2] - mn));
      pb.w = f2bf(__expf(st[tk][3] - mn));
      *(ushort4*)(pw + tk * 16 + lhi * 4) = pb;
      rs += bf2f(pb.x) + bf2f(pb.y) + bf2f(pb.z) + bf2f(pb.w);
    }
    rs += __shfl_xor(rs, 16);
    rs += __shfl_xor(rs, 32);
    l_i = l_i * a + rs;
    m_i = mn;

    float aR[4];
#pragma unroll
    for (int r = 0; r < 4; ++r) aR[r] = __shfl(a, lhi * 4 + r);
#pragma unroll
    for (int td = 0; td < 4; ++td)
#pragma unroll
      for (int r = 0; r < 4; ++r) o[td][r] *= aR[r];

    // O += P V (same-wave LDS write->read ordering, no barrier needed)
    bf16x8 pf0 = *(const bf16x8*)(pw + lhi * 8);
    bf16x8 pf1 = *(const bf16x8*)(pw + 32 + lhi * 8);
#pragma unroll
    for (int td = 0; td < 4; ++td) {
      const unsigned short* vr = bV + (td * 16 + llo) * 64;
      bf16x8 vf0 = *(const bf16x8*)(vr + cpos);
      bf16x8 vf1 = *(const bf16x8*)(vr + cposx);
      o[td] = mfma16(pf0, vf0, o[td]);
      o[td] = mfma16(pf1, vf1, o[td]);
    }
  }

  float lR[4];
#pragma unroll
  for (int r = 0; r < 4; ++r) lR[r] = 1.f / __shfl(l_i, lhi * 4 + r);
  const int b = bh >> 4, h = bh & 15;
#pragma unroll
  for (int td = 0; td < 4; ++td)
#pragma unroll
    for (int r = 0; r < 4; ++r) {
      int qr = q0 + wave * 16 + lhi * 4 + r;
      AO[(size_t)(b * 2048 + qr) * 1024 + h * 64 + td * 16 + llo] = f2bf(o[td][r] * lR[r]);
    }
}

// ---------------- output projection GEMM (128x128 tile, 512 threads) ---------------------
__global__ __launch_bounds__(512, 2) void out_gemm_kernel(const unsigned short* __restrict__ AO,
                                                          const unsigned short* __restrict__ Wt,
                                                          const float* __restrict__ bias,
                                                          float* __restrict__ out) {
  __shared__ __align__(16) unsigned short sA[3][128 * 32];
  __shared__ __align__(16) unsigned short sB[3][128 * 32];
  f32x4 acc[2][4];
  const int m0 = blockIdx.y * 128, n0 = blockIdx.x * 128;
  gemm_mainloop512<false, D_MODEL>(AO, Wt, m0, n0, sA[0], sB[0], acc);

  const int t = threadIdx.x, lane = t & 63, wave = t >> 6;
  const int wr = wave >> 1, wc = wave & 1, lhi = lane >> 4, llo = lane & 15;
#pragma unroll
  for (int ti = 0; ti < 2; ++ti)
#pragma unroll
    for (int tj = 0; tj < 4; ++tj) {
      int n = n0 + wc * 64 + tj * 16 + llo;
      float bv = bias[n];
#pragma unroll
      for (int r = 0; r < 4; ++r) {
        int m = m0 + wr * 32 + ti * 16 + lhi * 4 + r;
        out[(size_t)m * D_MODEL + n] = acc[ti][tj][r] + bv;
      }
    }
}

extern "C" void kernel_launch(void* const* d_in, const int* in_sizes, int n_in,
                              void* d_out, int out_size, void* d_ws, size_t ws_size,
                              hipStream_t stream) {
  const float* x      = (const float*)d_in[0];
  const float* qkv_w  = (const float*)d_in[1];
  const float* qkv_b  = (const float*)d_in[2];
  const float* out_w  = (const float*)d_in[3];
  const float* out_b  = (const float*)d_in[4];
  float* out = (float*)d_out;
  char* ws = (char*)d_ws;

  // workspace layout (48 MB total)
  unsigned short* Xb  = (unsigned short*)(ws);                          // 8 MB  x bf16
  unsigned short* Wq  = (unsigned short*)(ws + ((size_t)8  << 20));     // 6 MB  qkv_w^T bf16
  unsigned short* Wo  = (unsigned short*)(ws + ((size_t)14 << 20));     // 2 MB  out_w^T bf16
  unsigned short* Qw  = (unsigned short*)(ws + ((size_t)16 << 20));     // 8 MB  Q (bh,s,d)*1/8
  unsigned short* Kw  = (unsigned short*)(ws + ((size_t)24 << 20));     // 8 MB  K (bh,s,d)
  unsigned short* Vtw = (unsigned short*)(ws + ((size_t)32 << 20));     // 8 MB  V^T (bh,d,s)
  unsigned short* AO  = (unsigned short*)(ws + ((size_t)40 << 20));     // 8 MB  attn out (m,hd)

  prep_kernel<<<8192, 256, 0, stream>>>(x, qkv_w, out_w, Xb, Wq, Wo);
  qkv_gemm_kernel<<<dim3(NQKV / 256, MTOT / 256), 512, 0, stream>>>(Xb, Wq, qkv_b, Qw, Kw, Vtw);
  attn_kernel<<<dim3(BATCH * NUM_HEADS, SEQ / 128), 512, 0, stream>>>(Qw, Kw, Vtw, AO);
  out_gemm_kernel<<<dim3(D_MODEL / 128, MTOT / 128), 512, 0, stream>>>(AO, Wo, out_b, out);
}

// Round 2
// 169.009 us; speedup vs baseline: 1.0335x; 1.0335x over previous
//
#include <hip/hip_runtime.h>
#include <cstdint>
#include <cstddef>

#define NUM_HEADS 16
#define HEAD_DIM  64
#define WINDOW    512
#define D_MODEL   1024
#define BATCH     2
#define SEQ       2048
#define MTOT      (BATCH*SEQ)   // 4096
#define NQKV      (3*D_MODEL)   // 3072

typedef short bf16x8 __attribute__((ext_vector_type(8)));
typedef float f32x4  __attribute__((ext_vector_type(4)));

__device__ __forceinline__ f32x4 mfma16(bf16x8 a, bf16x8 b, f32x4 c) {
  return __builtin_amdgcn_mfma_f32_16x16x32_bf16(a, b, c, 0, 0, 0);
}

__device__ __forceinline__ unsigned short f2bf(float f) {
  unsigned int u = __float_as_uint(f);
  u += 0x7fffu + ((u >> 16) & 1u);
  return (unsigned short)(u >> 16);
}
__device__ __forceinline__ float bf2f(unsigned short b) {
  return __uint_as_float(((unsigned int)b) << 16);
}

// async global->LDS, 16B/lane; LDS dest = wave-uniform base + lane*16 (m104).
__device__ __forceinline__ void gld16(const unsigned short* g, unsigned short* l) {
  __builtin_amdgcn_global_load_lds(
      (const __attribute__((address_space(1))) unsigned int*)g,
      (__attribute__((address_space(3))) unsigned int*)l, 16, 0, 0);
}

// ---------------- fused prep: x->bf16 | qkv_w^T->bf16 | out_w^T->bf16 ----------------
__global__ __launch_bounds__(256) void prep_kernel(const float* __restrict__ x,
                                                   const float* __restrict__ qkv_w,
                                                   const float* __restrict__ out_w,
                                                   unsigned short* __restrict__ Xb,
                                                   unsigned short* __restrict__ Wq,
                                                   unsigned short* __restrict__ Wo) {
  __shared__ float tile[32][33];
  const int bid = blockIdx.x, t = threadIdx.x;
  if (bid < 4096) {
    int i = (bid * 256 + t) * 4;
    float4 v = *(const float4*)(x + i);
    ushort4 o;
    o.x = f2bf(v.x); o.y = f2bf(v.y); o.z = f2bf(v.z); o.w = f2bf(v.w);
    *(ushort4*)(Xb + i) = o;
    return;
  }
  const float* in; unsigned short* out; int R, C, bx, by;
  if (bid < 7168) { int b2 = bid - 4096; in = qkv_w; out = Wq; R = D_MODEL; C = NQKV; bx = b2 % 96; by = b2 / 96; }
  else            { int b2 = bid - 7168; in = out_w; out = Wo; R = D_MODEL; C = D_MODEL; bx = b2 & 31; by = b2 >> 5; }
  int tx = t & 31, ty = t >> 5;            // (32, 8)
  int c0 = bx * 32, r0 = by * 32;
#pragma unroll
  for (int i = 0; i < 32; i += 8)
    tile[ty + i][tx] = in[(size_t)(r0 + ty + i) * C + c0 + tx];
  __syncthreads();
#pragma unroll
  for (int i = 0; i < 32; i += 8)
    out[(size_t)(c0 + ty + i) * R + r0 + tx] = f2bf(tile[tx][ty + i]);
}

// ---------------- 512-thread 3-stage pipelined GEMM mainloop, XOR-swizzled LDS -----------
// (kept for out_gemm: grid there is 256 blocks at 2-3/CU; proven r0 structure)
template<bool SWAP, int K>
__device__ __forceinline__ void gemm_mainloop512(const unsigned short* __restrict__ A,
                                                 const unsigned short* __restrict__ Bt,
                                                 int m0, int n0,
                                                 unsigned short* sA, unsigned short* sB,
                                                 f32x4 (&acc)[2][4]) {
  const int t = threadIdx.x;
  const int lane = t & 63, wave = t >> 6;
  const int wr = wave >> 1, wc = wave & 1;   // 4x2 wave grid
  const int lhi = lane >> 4, llo = lane & 15;
  f32x4 zero = {0.f, 0.f, 0.f, 0.f};
#pragma unroll
  for (int i = 0; i < 2; ++i)
#pragma unroll
    for (int j = 0; j < 4; ++j) acc[i][j] = zero;

  const int cswz = (((t & 3) ^ ((t >> 3) & 3)) << 3);   // swizzled k-chunk for staging
  const unsigned short* gA = A  + (size_t)(m0 + (t >> 2)) * K + cswz;
  const unsigned short* gB = Bt + (size_t)(n0 + (t >> 2)) * K + cswz;
  const int ldsT = t * 8;
  const int rsw  = (lhi ^ ((llo >> 1) & 3)) * 8;        // swizzled chunk for frag reads
  const int aoff = (wr * 32 + llo) * 32 + rsw;
  const int boff = (wc * 64 + llo) * 32 + rsw;
  constexpr int nIter = K / 32;

  auto stage = [&](int s) {
    unsigned short* dA = sA + (s % 3) * 4096;
    unsigned short* dB = sB + (s % 3) * 4096;
    gld16(gA + s * 32, dA + ldsT);
    gld16(gB + s * 32, dB + ldsT);
  };

  stage(0);
  stage(1);
#pragma unroll
  for (int it = 0; it < nIter; ++it) {
    // wait tile `it` (2 oldest loads); keep tile `it+1` (2 newest) in flight
    if (it + 1 < nIter) asm volatile("s_waitcnt vmcnt(2)\n\ts_barrier" ::: "memory");
    else                asm volatile("s_waitcnt vmcnt(0)\n\ts_barrier" ::: "memory");
    if (it + 2 < nIter) stage(it + 2);
    const unsigned short* cA = sA + (it % 3) * 4096;
    const unsigned short* cB = sB + (it % 3) * 4096;
    bf16x8 af[2], bfr[4];
#pragma unroll
    for (int i = 0; i < 2; ++i) af[i]  = *(const bf16x8*)(cA + aoff + i * 512);
#pragma unroll
    for (int j = 0; j < 4; ++j)  bfr[j] = *(const bf16x8*)(cB + boff + j * 512);
#pragma unroll
    for (int i = 0; i < 2; ++i)
#pragma unroll
      for (int j = 0; j < 4; ++j)
        acc[i][j] = SWAP ? mfma16(bfr[j], af[i], acc[i][j])
                         : mfma16(af[i], bfr[j], acc[i][j]);
  }
}

// ---------------- 256x256-tile 4-phase/K-64 mainloop (m201-style, slice-granular) --------
// 8 waves 2(M)x4(N), wave tile 128x64, acc[8][4]. K-tile = 64, processed as 4 quadrant
// phases (mh,nh) in {0,1}^2; each phase: 12 ds_read_b128 + stage-1-slice + barrier +
// 16 MFMA (setprio-wrapped). Slice = exactly what one phase consumes (16 KB):
//   A-slice(mh): global rows {m0+mh*64+q} u {m0+128+mh*64+q}, q=0..63 -> local [128][64]
//   B-slice(nh): global cols {n0+wcq*64+nh*32+r}, wcq=0..3,r=0..31    -> local [128][64]
// Staging schedule sigma (stage at phase p of tile j): p0:B0(j+1) p1:B1(j+1) p2:A1(j+1)
// p3:A0(j+2). Every slice is staged >=4 slice-slots before first use, so vmcnt(6)
// (=3 slices in flight) at each phase head forces it landed; slot overwrite is always
// >=2 barriers after the slot's last read (hand-verified dependence table).
// vmcnt never drains to 0 until the peeled last tile (4/2/0). LDS 128 KB -> 1 block/CU.
template<bool SWAP>
__device__ __forceinline__ void gemm_mainloop_256q(const unsigned short* __restrict__ A,
                                                   const unsigned short* __restrict__ Bt,
                                                   int m0, int n0,
                                                   unsigned short* sA, unsigned short* sB,
                                                   f32x4 (&acc)[8][4]) {
  constexpr int K = D_MODEL;       // 1024
  constexpr int nT = K / 64;       // 16 K-tiles
  const int t = threadIdx.x, lane = t & 63, wave = t >> 6;
  const int wr = wave >> 2, wc = wave & 3;      // 2(M) x 4(N) wave grid
  const int lhi = lane >> 4, llo = lane & 15;
  f32x4 zero = {0.f, 0.f, 0.f, 0.f};
#pragma unroll
  for (int i = 0; i < 8; ++i)
#pragma unroll
    for (int j = 0; j < 4; ++j) acc[i][j] = zero;

  // staging: thread t covers local rows (t>>3) and 64+(t>>3), k-chunk (t&7), with the
  // global source pre-swizzled by the row-XOR so linear LDS writes land swizzled (m173).
  const int r6 = t >> 3;                         // 0..63
  const int chunkS = (t & 7) ^ (r6 & 7);
  const unsigned short* gAr = A  + (size_t)(m0 + r6) * K + chunkS * 8;
  const unsigned short* gBr = Bt + (size_t)(n0 + (r6 >> 5) * 64 + (r6 & 31)) * K + chunkS * 8;
  const int dstT = t * 8;

  // frag reads: elem offset = lr*64 + ((kk*4+lhi)^(lr&7))*8, lr&7 == llo&7
  const int k0off = (lhi ^ (llo & 7)) * 8;
  const int k1off = k0off ^ 32;
  const int aRow = (wr * 64 + llo) * 64;         // + i2*1024
  const int bRow = (wc * 32 + llo) * 64;         // + j2*1024

  auto stA = [&](int j, int mh) {
    unsigned short* d = sA + (((j & 1) << 1) + mh) * 8192 + dstT;
    const unsigned short* g = gAr + (size_t)(mh * 64) * K + j * 64;
    gld16(g, d);
    gld16(g + (size_t)128 * K, d + 4096);
  };
  auto stB = [&](int j, int nh) {
    unsigned short* d = sB + (((j & 1) << 1) + nh) * 8192 + dstT;
    const unsigned short* g = gBr + (size_t)(nh * 32) * K + j * 64;
    gld16(g, d);
    gld16(g + (size_t)128 * K, d + 4096);
  };

#define QPHASE(JV, MH, NH, STG)                                                  \
  {                                                                              \
    const unsigned short* cA = sA + ((((JV) & 1) << 1) + (MH)) * 8192;           \
    const unsigned short* cB = sB + ((((JV) & 1) << 1) + (NH)) * 8192;           \
    bf16x8 af[4][2], bfv[2][2];                                                  \
    _Pragma("unroll") for (int i2 = 0; i2 < 4; ++i2) {                           \
      af[i2][0] = *(const bf16x8*)(cA + aRow + i2 * 1024 + k0off);               \
      af[i2][1] = *(const bf16x8*)(cA + aRow + i2 * 1024 + k1off);               \
    }                                                                            \
    _Pragma("unroll") for (int j2 = 0; j2 < 2; ++j2) {                           \
      bfv[j2][0] = *(const bf16x8*)(cB + bRow + j2 * 1024 + k0off);              \
      bfv[j2][1] = *(const bf16x8*)(cB + bRow + j2 * 1024 + k1off);              \
    }                                                                            \
    STG;                                                                         \
    asm volatile("s_barrier" ::: "memory");                                      \
    __builtin_amdgcn_s_setprio(1);                                               \
    _Pragma("unroll") for (int i2 = 0; i2 < 4; ++i2)                             \
      _Pragma("unroll") for (int j2 = 0; j2 < 2; ++j2) {                         \
        f32x4& ac = acc[(MH) * 4 + i2][(NH) * 2 + j2];                           \
        ac = SWAP ? mfma16(bfv[j2][0], af[i2][0], ac)                            \
                  : mfma16(af[i2][0], bfv[j2][0], ac);                           \
        ac = SWAP ? mfma16(bfv[j2][1], af[i2][1], ac)                            \
                  : mfma16(af[i2][1], bfv[j2][1], ac);                           \
      }                                                                          \
    __builtin_amdgcn_s_setprio(0);                                               \
  }

  // prologue: exactly the steady-state staging prefix [A0(0) B0(0) B1(0) A1(0) A0(1)]
  stA(0, 0); stB(0, 0); stB(0, 1); stA(0, 1); stA(1, 0);

  for (int j = 0; j < nT - 1; ++j) {
    asm volatile("s_waitcnt vmcnt(6)\n\ts_barrier" ::: "memory");
    QPHASE(j, 0, 0, { stB(j + 1, 0); });
    asm volatile("s_waitcnt vmcnt(6)\n\ts_barrier" ::: "memory");
    QPHASE(j, 0, 1, { stB(j + 1, 1); });
    asm volatile("s_waitcnt vmcnt(6)\n\ts_barrier" ::: "memory");
    QPHASE(j, 1, 0, { stA(j + 1, 1); });
    asm volatile("s_waitcnt vmcnt(6)\n\ts_barrier" ::: "memory");
    QPHASE(j, 1, 1, { if (j + 2 < nT) stA(j + 2, 0); });
  }
  // peeled last tile: drain 4 -> 2 -> 0
  asm volatile("s_waitcnt vmcnt(4)\n\ts_barrier" ::: "memory");
  QPHASE(nT - 1, 0, 0, {});
  asm volatile("s_waitcnt vmcnt(2)\n\ts_barrier" ::: "memory");
  QPHASE(nT - 1, 0, 1, {});
  asm volatile("s_waitcnt vmcnt(0)\n\ts_barrier" ::: "memory");
  QPHASE(nT - 1, 1, 0, {});
  asm volatile("s_barrier" ::: "memory");
  QPHASE(nT - 1, 1, 1, {});
#undef QPHASE
}

// ---------------- QKV projection GEMM (256x256 tile, 512 threads) ------------------------
// n0 < 2048: Q/K, normal orientation, coalesced (bh,s,d) stores.
// n0 >= 2048: V, transposed accumulator, DIRECT V^T (bh,d,s) stores.
// 256-tiles never straddle the Q/K/V boundaries (1024 & 2048 are multiples of 256).
__global__ __launch_bounds__(512, 2) void qkv_gemm_kernel(const unsigned short* __restrict__ Xb,
                                                          const unsigned short* __restrict__ Wt,
                                                          const float* __restrict__ bias,
                                                          unsigned short* __restrict__ Qw,
                                                          unsigned short* __restrict__ Kw,
                                                          unsigned short* __restrict__ Vtw) {
  __shared__ __align__(16) unsigned short sA[2 * 2 * 8192];   // 64 KB (dbuf x mh-slice)
  __shared__ __align__(16) unsigned short sB[2 * 2 * 8192];   // 64 KB (dbuf x nh-slice)
  f32x4 acc[8][4];
  const int m0 = blockIdx.y * 256, n0 = blockIdx.x * 256;
  const int t = threadIdx.x, lane = t & 63, wave = t >> 6;
  const int wr = wave >> 2, wc = wave & 3, lhi = lane >> 4, llo = lane & 15;

  if (n0 < 2048) {
    gemm_mainloop_256q<false>(Xb, Wt, m0, n0, sA, sB, acc);
    const int c = n0 >> 10;     // block-uniform: Q or K
    unsigned short* __restrict__ Dst = (c == 0) ? Qw : Kw;
    const float qs = (c == 0) ? 0.125f : 1.0f;
#pragma unroll
    for (int mi = 0; mi < 8; ++mi) {
#pragma unroll
      for (int nj = 0; nj < 4; ++nj) {
        int n = n0 + wc * 64 + nj * 16 + llo;
        float bv = bias[n];
        int h = (n >> 6) & 15, d = n & 63;
#pragma unroll
        for (int r = 0; r < 4; ++r) {
          int m = m0 + wr * 128 + mi * 16 + lhi * 4 + r;
          int b = m >> 11, s = m & 2047;
          int bh = b * 16 + h;
          Dst[((size_t)(bh * 2048 + s)) * 64 + d] = f2bf((acc[mi][nj][r] + bv) * qs);
        }
      }
    }
  } else {
    gemm_mainloop_256q<true>(Xb, Wt, m0, n0, sA, sB, acc);
#pragma unroll
    for (int mi = 0; mi < 8; ++mi) {
      int m = m0 + wr * 128 + mi * 16 + llo;   // s-dim (col of C^T)
      int b = m >> 11, s = m & 2047;
#pragma unroll
      for (int nj = 0; nj < 4; ++nj) {
        int nb = n0 + wc * 64 + nj * 16 + lhi * 4;   // d-base (row of C^T), 4-aligned
        float4 bv = *(const float4*)(bias + nb);
        int h = (nb >> 6) & 15, dbase = nb & 63;
        int bh = b * 16 + h;
        float bvr[4] = {bv.x, bv.y, bv.z, bv.w};
#pragma unroll
        for (int r = 0; r < 4; ++r)
          Vtw[(size_t)(bh * 64 + dbase + r) * 2048 + s] = f2bf(acc[mi][nj][r] + bvr[r]);
      }
    }
  }
}

// ---------------- flash sliding-window attention (S^T, 512 threads, 3-stage K/V) ---------
__global__ __launch_bounds__(512) void attn_kernel(const unsigned short* __restrict__ Qw,
                                                   const unsigned short* __restrict__ Kw,
                                                   const unsigned short* __restrict__ Vtw,
                                                   unsigned short* __restrict__ AO) {
  __shared__ __align__(16) unsigned short sK[3][64 * 64];  // (key,d), XOR-swizzled chunks
  __shared__ __align__(16) unsigned short sV[3][64 * 64];  // (d,key), XOR-swizzled chunks
  __shared__ __align__(16) unsigned short sP[8][16 * 72];  // per-wave P (query,key), pad 72
  const int t = threadIdx.x, lane = t & 63, wave = t >> 6;  // wave 0..7
  const int lhi = lane >> 4, llo = lane & 15;
  const int bh = blockIdx.x;                 // bh%8 -> XCD; q-tiles of bh share L2
  const int q0 = (15 - blockIdx.y) << 7;     // heaviest q-tiles dispatch first
  const unsigned short* Qb = Qw  + (size_t)bh * 2048 * 64;
  const unsigned short* Kb = Kw  + (size_t)bh * 2048 * 64;
  const unsigned short* Vb = Vtw + (size_t)bh * 64 * 2048;

  const int qw = q0 + wave * 16;             // this wave's query base
  const int qrow = qw + llo;                 // this lane's query (column of S^T)
  bf16x8 qf0 = *(const bf16x8*)(Qb + (size_t)qrow * 64 + lhi * 8);
  bf16x8 qf1 = *(const bf16x8*)(Qb + (size_t)qrow * 64 + 32 + lhi * 8);

  const int srow = t >> 3;                   // 512 threads cover a full 64x64 bf16 tile
  const int scol = ((t & 7) ^ (srow & 7)) * 8;   // XOR-swizzled staging chunk
  const int cpos  = (lhi ^ (llo & 7)) * 8;       // swizzled chunk for frag reads
  const int cposx = cpos ^ 32;                   // chunk c^4

  float m_i = -1e30f, l_i = 0.f;
  f32x4 o[4];
  f32x4 zero = {0.f, 0.f, 0.f, 0.f};
#pragma unroll
  for (int td = 0; td < 4; ++td) o[td] = zero;

  const int kt_lo = (q0 > 511) ? ((q0 - 511) >> 6) : 0;
  const int kt_hi = (q0 + 127) >> 6;         // every block has >= 2 k-tiles

  auto stageKV = [&](int j) {
    const int k0 = j << 6;
    unsigned short* dK = sK[j % 3];
    unsigned short* dV = sV[j % 3];
    gld16(Kb + (size_t)(k0 + srow) * 64 + scol, dK + t * 8);
    gld16(Vb + (size_t)srow * 2048 + k0 + scol, dV + t * 8);
  };

  stageKV(kt_lo);
  stageKV(kt_lo + 1);

  for (int kt = kt_lo; kt <= kt_hi; ++kt) {
    // wait for tile kt (2 oldest); keep tile kt+1 (2 newest) in flight across barrier
    if (kt < kt_hi) asm volatile("s_waitcnt vmcnt(2)\n\ts_barrier" ::: "memory");
    else            asm volatile("s_waitcnt vmcnt(0)\n\ts_barrier" ::: "memory");
    if (kt + 2 <= kt_hi) stageKV(kt + 2);
    const int k0 = kt << 6;
    // per-wave uniform skip: wave queries qw..qw+15, window union [qw-511, qw+15]
    if (k0 > qw + 15 || k0 + 63 < qw - (WINDOW - 1)) continue;  // no barrier inside

    const unsigned short* bK = sK[kt % 3];
    const unsigned short* bV = sV[kt % 3];

    // S^T tiles: row = key (tk*16 + lhi*4 + r), col = query (llo)
    f32x4 st[4];
#pragma unroll
    for (int tk = 0; tk < 4; ++tk) {
      const unsigned short* kr = bK + (tk * 16 + llo) * 64;
      bf16x8 kf0 = *(const bf16x8*)(kr + cpos);
      bf16x8 kf1 = *(const bf16x8*)(kr + cposx);
      f32x4 z = zero;
      z = mfma16(kf0, qf0, z);
      z = mfma16(kf1, qf1, z);
      st[tk] = z;
    }

    // wave-uniform interior fast path: all 16 keysx queries valid -> skip masking
    const bool interior = (k0 >= qw - (WINDOW - 1 - 15)) && (k0 + 63 <= qw);
    const int kb = k0 + lhi * 4;
    float mx = -1e30f;
    if (interior) {
#pragma unroll
      for (int tk = 0; tk < 4; ++tk)
#pragma unroll
        for (int r = 0; r < 4; ++r) mx = fmaxf(mx, st[tk][r]);
    } else {
#pragma unroll
      for (int tk = 0; tk < 4; ++tk)
#pragma unroll
        for (int r = 0; r < 4; ++r) {
          int key = kb + tk * 16 + r;
          bool ok = (key <= qrow) && (qrow - key < WINDOW);
          float s = ok ? st[tk][r] : -1e30f;
          st[tk][r] = s;
          mx = fmaxf(mx, s);
        }
    }
    mx = fmaxf(mx, __shfl_xor(mx, 16));
    mx = fmaxf(mx, __shfl_xor(mx, 32));
    float mn = fmaxf(m_i, mx);
    float a  = __expf(m_i - mn);  // fully-masked tile garbage wiped by a=0 on next real tile
    float rs = 0.f;
    unsigned short* pw = &sP[wave][llo * 72];
#pragma unroll
    for (int tk = 0; tk < 4; ++tk) {
      ushort4 pb;
      pb.x = f2bf(__expf(st[tk][0] - mn));
      pb.y = f2bf(__expf(st[tk][1] - mn));
      pb.z = f2bf(__expf(st[tk][2] - mn));
      pb.w = f2bf(__expf(st[tk][3] - mn));
      *(ushort4*)(pw + tk * 16 + lhi * 4) = pb;
      rs += bf2f(pb.x) + bf2f(pb.y) + bf2f(pb.z) + bf2f(pb.w);
    }
    rs += __shfl_xor(rs, 16);
    rs += __shfl_xor(rs, 32);
    l_i = l_i * a + rs;
    m_i = mn;

    float aR[4];
#pragma unroll
    for (int r = 0; r < 4; ++r) aR[r] = __shfl(a, lhi * 4 + r);
#pragma unroll
    for (int td = 0; td < 4; ++td)
#pragma unroll
      for (int r = 0; r < 4; ++r) o[td][r] *= aR[r];

    // O += P V (same-wave LDS write->read ordering, no barrier needed)
    bf16x8 pf0 = *(const bf16x8*)(pw + lhi * 8);
    bf16x8 pf1 = *(const bf16x8*)(pw + 32 + lhi * 8);
#pragma unroll
    for (int td = 0; td < 4; ++td) {
      const unsigned short* vr = bV + (td * 16 + llo) * 64;
      bf16x8 vf0 = *(const bf16x8*)(vr + cpos);
      bf16x8 vf1 = *(const bf16x8*)(vr + cposx);
      o[td] = mfma16(pf0, vf0, o[td]);
      o[td] = mfma16(pf1, vf1, o[td]);
    }
  }

  float lR[4];
#pragma unroll
  for (int r = 0; r < 4; ++r) lR[r] = 1.f / __shfl(l_i, lhi * 4 + r);
  const int b = bh >> 4, h = bh & 15;
#pragma unroll
  for (int td = 0; td < 4; ++td)
#pragma unroll
    for (int r = 0; r < 4; ++r) {
      int qr = q0 + wave * 16 + lhi * 4 + r;
      AO[(size_t)(b * 2048 + qr) * 1024 + h * 64 + td * 16 + llo] = f2bf(o[td][r] * lR[r]);
    }
}

// ---------------- output projection GEMM (128x128 tile, 512 threads) ---------------------
__global__ __launch_bounds__(512, 2) void out_gemm_kernel(const unsigned short* __restrict__ AO,
                                                          const unsigned short* __restrict__ Wt,
                                                          const float* __restrict__ bias,
                                                          float* __restrict__ out) {
  __shared__ __align__(16) unsigned short sA[3][128 * 32];
  __shared__ __align__(16) unsigned short sB[3][128 * 32];
  f32x4 acc[2][4];
  const int m0 = blockIdx.y * 128, n0 = blockIdx.x * 128;
  gemm_mainloop512<false, D_MODEL>(AO, Wt, m0, n0, sA[0], sB[0], acc);

  const int t = threadIdx.x, lane = t & 63, wave = t >> 6;
  const int wr = wave >> 1, wc = wave & 1, lhi = lane >> 4, llo = lane & 15;
#pragma unroll
  for (int ti = 0; ti < 2; ++ti)
#pragma unroll
    for (int tj = 0; tj < 4; ++tj) {
      int n = n0 + wc * 64 + tj * 16 + llo;
      float bv = bias[n];
#pragma unroll
      for (int r = 0; r < 4; ++r) {
        int m = m0 + wr * 32 + ti * 16 + lhi * 4 + r;
        out[(size_t)m * D_MODEL + n] = acc[ti][tj][r] + bv;
      }
    }
}

extern "C" void kernel_launch(void* const* d_in, const int* in_sizes, int n_in,
                              void* d_out, int out_size, void* d_ws, size_t ws_size,
                              hipStream_t stream) {
  const float* x      = (const float*)d_in[0];
  const float* qkv_w  = (const float*)d_in[1];
  const float* qkv_b  = (const float*)d_in[2];
  const float* out_w  = (const float*)d_in[3];
  const float* out_b  = (const float*)d_in[4];
  float* out = (float*)d_out;
  char* ws = (char*)d_ws;

  // workspace layout (48 MB total)
  unsigned short* Xb  = (unsigned short*)(ws);                          // 8 MB  x bf16
  unsigned short* Wq  = (unsigned short*)(ws + ((size_t)8  << 20));     // 6 MB  qkv_w^T bf16
  unsigned short* Wo  = (unsigned short*)(ws + ((size_t)14 << 20));     // 2 MB  out_w^T bf16
  unsigned short* Qw  = (unsigned short*)(ws + ((size_t)16 << 20));     // 8 MB  Q (bh,s,d)*1/8
  unsigned short* Kw  = (unsigned short*)(ws + ((size_t)24 << 20));     // 8 MB  K (bh,s,d)
  unsigned short* Vtw = (unsigned short*)(ws + ((size_t)32 << 20));     // 8 MB  V^T (bh,d,s)
  unsigned short* AO  = (unsigned short*)(ws + ((size_t)40 << 20));     // 8 MB  attn out (m,hd)

  prep_kernel<<<8192, 256, 0, stream>>>(x, qkv_w, out_w, Xb, Wq, Wo);
  qkv_gemm_kernel<<<dim3(NQKV / 256, MTOT / 256), 512, 0, stream>>>(Xb, Wq, qkv_b, Qw, Kw, Vtw);
  attn_kernel<<<dim3(BATCH * NUM_HEADS, SEQ / 128), 512, 0, stream>>>(Qw, Kw, Vtw, AO);
  out_gemm_kernel<<<dim3(D_MODEL / 128, MTOT / 128), 512, 0, stream>>>(AO, Wo, out_b, out);
}

// Round 3
// 166.202 us; speedup vs baseline: 1.0509x; 1.0169x over previous
//
#include <hip/hip_runtime.h>
#include <cstdint>
#include <cstddef>

#define NUM_HEADS 16
#define HEAD_DIM  64
#define WINDOW    512
#define D_MODEL   1024
#define BATCH     2
#define SEQ       2048
#define MTOT      (BATCH*SEQ)   // 4096
#define NQKV      (3*D_MODEL)   // 3072

typedef short bf16x8 __attribute__((ext_vector_type(8)));
typedef float f32x4  __attribute__((ext_vector_type(4)));

__device__ __forceinline__ f32x4 mfma16(bf16x8 a, bf16x8 b, f32x4 c) {
  return __builtin_amdgcn_mfma_f32_16x16x32_bf16(a, b, c, 0, 0, 0);
}

__device__ __forceinline__ unsigned short f2bf(float f) {
  unsigned int u = __float_as_uint(f);
  u += 0x7fffu + ((u >> 16) & 1u);
  return (unsigned short)(u >> 16);
}
__device__ __forceinline__ float bf2f(unsigned short b) {
  return __uint_as_float(((unsigned int)b) << 16);
}

// async global->LDS, 16B/lane; LDS dest = wave-uniform base + lane*16 (m104).
__device__ __forceinline__ void gld16(const unsigned short* g, unsigned short* l) {
  __builtin_amdgcn_global_load_lds(
      (const __attribute__((address_space(1))) unsigned int*)g,
      (__attribute__((address_space(3))) unsigned int*)l, 16, 0, 0);
}

// ---------------- fused prep: x->bf16 | qkv_w^T->bf16 | out_w^T->bf16 ----------------
__global__ __launch_bounds__(256) void prep_kernel(const float* __restrict__ x,
                                                   const float* __restrict__ qkv_w,
                                                   const float* __restrict__ out_w,
                                                   unsigned short* __restrict__ Xb,
                                                   unsigned short* __restrict__ Wq,
                                                   unsigned short* __restrict__ Wo) {
  __shared__ float tile[32][33];
  const int bid = blockIdx.x, t = threadIdx.x;
  if (bid < 4096) {
    int i = (bid * 256 + t) * 4;
    float4 v = *(const float4*)(x + i);
    ushort4 o;
    o.x = f2bf(v.x); o.y = f2bf(v.y); o.z = f2bf(v.z); o.w = f2bf(v.w);
    *(ushort4*)(Xb + i) = o;
    return;
  }
  const float* in; unsigned short* out; int R, C, bx, by;
  if (bid < 7168) { int b2 = bid - 4096; in = qkv_w; out = Wq; R = D_MODEL; C = NQKV; bx = b2 % 96; by = b2 / 96; }
  else            { int b2 = bid - 7168; in = out_w; out = Wo; R = D_MODEL; C = D_MODEL; bx = b2 & 31; by = b2 >> 5; }
  int tx = t & 31, ty = t >> 5;            // (32, 8)
  int c0 = bx * 32, r0 = by * 32;
#pragma unroll
  for (int i = 0; i < 32; i += 8)
    tile[ty + i][tx] = in[(size_t)(r0 + ty + i) * C + c0 + tx];
  __syncthreads();
#pragma unroll
  for (int i = 0; i < 32; i += 8)
    out[(size_t)(c0 + ty + i) * R + r0 + tx] = f2bf(tile[tx][ty + i]);
}

// ---------------- 512-thread 3-stage pipelined GEMM mainloop, XOR-swizzled LDS -----------
// (kept for out_gemm: grid there is 256 blocks at 2-3/CU; proven r0 structure)
template<bool SWAP, int K>
__device__ __forceinline__ void gemm_mainloop512(const unsigned short* __restrict__ A,
                                                 const unsigned short* __restrict__ Bt,
                                                 int m0, int n0,
                                                 unsigned short* sA, unsigned short* sB,
                                                 f32x4 (&acc)[2][4]) {
  const int t = threadIdx.x;
  const int lane = t & 63, wave = t >> 6;
  const int wr = wave >> 1, wc = wave & 1;   // 4x2 wave grid
  const int lhi = lane >> 4, llo = lane & 15;
  f32x4 zero = {0.f, 0.f, 0.f, 0.f};
#pragma unroll
  for (int i = 0; i < 2; ++i)
#pragma unroll
    for (int j = 0; j < 4; ++j) acc[i][j] = zero;

  const int cswz = (((t & 3) ^ ((t >> 3) & 3)) << 3);   // swizzled k-chunk for staging
  const unsigned short* gA = A  + (size_t)(m0 + (t >> 2)) * K + cswz;
  const unsigned short* gB = Bt + (size_t)(n0 + (t >> 2)) * K + cswz;
  const int ldsT = t * 8;
  const int rsw  = (lhi ^ ((llo >> 1) & 3)) * 8;        // swizzled chunk for frag reads
  const int aoff = (wr * 32 + llo) * 32 + rsw;
  const int boff = (wc * 64 + llo) * 32 + rsw;
  constexpr int nIter = K / 32;

  auto stage = [&](int s) {
    unsigned short* dA = sA + (s % 3) * 4096;
    unsigned short* dB = sB + (s % 3) * 4096;
    gld16(gA + s * 32, dA + ldsT);
    gld16(gB + s * 32, dB + ldsT);
  };

  stage(0);
  stage(1);
#pragma unroll
  for (int it = 0; it < nIter; ++it) {
    // wait tile `it` (2 oldest loads); keep tile `it+1` (2 newest) in flight
    if (it + 1 < nIter) asm volatile("s_waitcnt vmcnt(2)\n\ts_barrier" ::: "memory");
    else                asm volatile("s_waitcnt vmcnt(0)\n\ts_barrier" ::: "memory");
    if (it + 2 < nIter) stage(it + 2);
    const unsigned short* cA = sA + (it % 3) * 4096;
    const unsigned short* cB = sB + (it % 3) * 4096;
    bf16x8 af[2], bfr[4];
#pragma unroll
    for (int i = 0; i < 2; ++i) af[i]  = *(const bf16x8*)(cA + aoff + i * 512);
#pragma unroll
    for (int j = 0; j < 4; ++j)  bfr[j] = *(const bf16x8*)(cB + boff + j * 512);
#pragma unroll
    for (int i = 0; i < 2; ++i)
#pragma unroll
      for (int j = 0; j < 4; ++j)
        acc[i][j] = SWAP ? mfma16(bfr[j], af[i], acc[i][j])
                         : mfma16(af[i], bfr[j], acc[i][j]);
  }
}

// ---------------- 256x256-tile 4-phase/K-64 mainloop, register-reuse (m201-style) --------
// 8 waves 2(M)x4(N), wave tile 128x64, acc[8][4]. K-tile = 64 = 4 quadrant phases
// ordered (0,0)->(0,1)->(1,1)->(1,0) with REGISTER reuse across phases:
//   P1 reads A0 (8 ds_read_b128) + B0 (4); P2 reads B1 (4, reuses A0);
//   P3 reads A1 (8, reuses B1);            P4 reads nothing (reuses A1 + B0 held).
// => 24 reads/wave/K-tile (was 48 in r2): LDS ~1550cy < MFMA ~2480cy per CU -> MFMA-bound.
// Staging (2 gld16 = 1 half-tile per phase), >=3-phase landing window per slice:
//   P1: stA(j+1,0)  P2: stB(j+1,0)  P3: stB(j+1,1)  P4: stA(j+1,1)
// Counted vmcnt(4) in P1/P2/P4 clusters (never 0 in main loop; peel drains 2->0):
//   P4's vmcnt(4)+barriers protect P1(j+1) reads of A',B0'; P1's protect P2's B1;
//   P2's protect P3's A1. Each phase: [reads|stage|vmcnt] barrier lgkmcnt(0)
//   sched_barrier setprio(1) 16xMFMA setprio(0) barrier.  (All RAW/WAR hand-verified.)
template<bool SWAP>
__device__ __forceinline__ void gemm_mainloop_256q(const unsigned short* __restrict__ A,
                                                   const unsigned short* __restrict__ Bt,
                                                   int m0, int n0,
                                                   unsigned short* sA, unsigned short* sB,
                                                   f32x4 (&acc)[8][4]) {
  constexpr int K = D_MODEL;       // 1024
  constexpr int nT = K / 64;       // 16 K-tiles
  const int t = threadIdx.x, lane = t & 63, wave = t >> 6;
  const int wr = wave >> 2, wc = wave & 3;      // 2(M) x 4(N) wave grid
  const int lhi = lane >> 4, llo = lane & 15;
  f32x4 zero = {0.f, 0.f, 0.f, 0.f};
#pragma unroll
  for (int i = 0; i < 8; ++i)
#pragma unroll
    for (int j = 0; j < 4; ++j) acc[i][j] = zero;

  // staging: thread t covers local rows (t>>3) and 64+(t>>3), k-chunk (t&7), with the
  // global source pre-swizzled by the row-XOR so linear LDS writes land swizzled (m173).
  const int r6 = t >> 3;                         // 0..63
  const int chunkS = (t & 7) ^ (r6 & 7);
  const unsigned short* gAr = A  + (size_t)(m0 + r6) * K + chunkS * 8;
  const unsigned short* gBr = Bt + (size_t)(n0 + (r6 >> 5) * 64 + (r6 & 31)) * K + chunkS * 8;
  const int dstT = t * 8;

  // frag reads: elem offset = lr*64 + ((kk*4+lhi)^(lr&7))*8, lr&7 == llo&7
  const int k0off = (lhi ^ (llo & 7)) * 8;
  const int k1off = k0off ^ 32;
  const int aRow = (wr * 64 + llo) * 64;         // + mi*1024
  const int bRow = (wc * 32 + llo) * 64;         // + nj*1024

  auto stA = [&](int j, int mh) {
    unsigned short* d = sA + ((j & 1) * 2 + mh) * 8192 + dstT;
    const unsigned short* g = gAr + (size_t)(mh * 64) * K + j * 64;
    gld16(g, d);
    gld16(g + (size_t)128 * K, d + 4096);
  };
  auto stB = [&](int j, int nh) {
    unsigned short* d = sB + ((j & 1) * 2 + nh) * 8192 + dstT;
    const unsigned short* g = gBr + (size_t)(nh * 32) * K + j * 64;
    gld16(g, d);
    gld16(g + (size_t)128 * K, d + 4096);
  };
  auto rdA = [&](bf16x8 (&af)[4][2], int j, int mh) {
    const unsigned short* cA = sA + ((j & 1) * 2 + mh) * 8192;
#pragma unroll
    for (int mi = 0; mi < 4; ++mi) {
      af[mi][0] = *(const bf16x8*)(cA + aRow + mi * 1024 + k0off);
      af[mi][1] = *(const bf16x8*)(cA + aRow + mi * 1024 + k1off);
    }
  };
  auto rdB = [&](bf16x8 (&bf)[2][2], int j, int nh) {
    const unsigned short* cB = sB + ((j & 1) * 2 + nh) * 8192;
#pragma unroll
    for (int nj = 0; nj < 2; ++nj) {
      bf[nj][0] = *(const bf16x8*)(cB + bRow + nj * 1024 + k0off);
      bf[nj][1] = *(const bf16x8*)(cB + bRow + nj * 1024 + k1off);
    }
  };

#define MFMA_QUAD(MH, NH, AF, BF)                                        \
  __builtin_amdgcn_s_setprio(1);                                         \
  _Pragma("unroll") for (int mi = 0; mi < 4; ++mi)                       \
    _Pragma("unroll") for (int nj = 0; nj < 2; ++nj) {                   \
      f32x4& ac = acc[(MH) * 4 + mi][(NH) * 2 + nj];                     \
      ac = SWAP ? mfma16(BF[nj][0], AF[mi][0], ac)                       \
                : mfma16(AF[mi][0], BF[nj][0], ac);                      \
      ac = SWAP ? mfma16(BF[nj][1], AF[mi][1], ac)                       \
                : mfma16(AF[mi][1], BF[nj][1], ac);                      \
    }                                                                    \
  __builtin_amdgcn_s_setprio(0);

  // prologue: stage tile 0's four half-tiles; retire the first two (A0,B0)
  stA(0, 0); stB(0, 0); stB(0, 1); stA(0, 1);
  asm volatile("s_waitcnt vmcnt(4)" ::: "memory");
  __builtin_amdgcn_s_barrier();

  bf16x8 a[4][2], b0[2][2], b1[2][2];
  for (int j = 0; j < nT - 1; ++j) {
    // ---- P1: quadrant (0,0) ----
    rdA(a, j, 0); rdB(b0, j, 0);
    stA(j + 1, 0);
    asm volatile("s_waitcnt vmcnt(4) lgkmcnt(8)" ::: "memory");   // retire B1(j) for P2
    __builtin_amdgcn_s_barrier();
    asm volatile("s_waitcnt lgkmcnt(0)" ::: "memory");
    __builtin_amdgcn_sched_barrier(0);
    MFMA_QUAD(0, 0, a, b0);
    __builtin_amdgcn_s_barrier();
    // ---- P2: quadrant (0,1) ----
    rdB(b1, j, 1);
    stB(j + 1, 0);
    asm volatile("s_waitcnt vmcnt(4)" ::: "memory");              // retire A1(j) for P3
    __builtin_amdgcn_s_barrier();
    asm volatile("s_waitcnt lgkmcnt(0)" ::: "memory");
    __builtin_amdgcn_sched_barrier(0);
    MFMA_QUAD(0, 1, a, b1);
    __builtin_amdgcn_s_barrier();
    // ---- P3: quadrant (1,1) ----
    rdA(a, j, 1);
    stB(j + 1, 1);
    __builtin_amdgcn_s_barrier();
    asm volatile("s_waitcnt lgkmcnt(0)" ::: "memory");
    __builtin_amdgcn_sched_barrier(0);
    MFMA_QUAD(1, 1, a, b1);
    __builtin_amdgcn_s_barrier();
    // ---- P4: quadrant (1,0) ----
    stA(j + 1, 1);
    asm volatile("s_waitcnt vmcnt(4)" ::: "memory");              // retire A0',B0' for P1'
    __builtin_amdgcn_s_barrier();
    __builtin_amdgcn_sched_barrier(0);
    MFMA_QUAD(1, 0, a, b0);
    __builtin_amdgcn_s_barrier();
  }
  // ---- peeled last tile: drain 2 -> 0 ----
  {
    const int j = nT - 1;
    rdA(a, j, 0); rdB(b0, j, 0);
    asm volatile("s_waitcnt vmcnt(2) lgkmcnt(8)" ::: "memory");   // retire B1(last)
    __builtin_amdgcn_s_barrier();
    asm volatile("s_waitcnt lgkmcnt(0)" ::: "memory");
    __builtin_amdgcn_sched_barrier(0);
    MFMA_QUAD(0, 0, a, b0);
    __builtin_amdgcn_s_barrier();
    rdB(b1, j, 1);
    asm volatile("s_waitcnt vmcnt(0)" ::: "memory");              // retire A1(last)
    __builtin_amdgcn_s_barrier();
    asm volatile("s_waitcnt lgkmcnt(0)" ::: "memory");
    __builtin_amdgcn_sched_barrier(0);
    MFMA_QUAD(0, 1, a, b1);
    __builtin_amdgcn_s_barrier();
    rdA(a, j, 1);
    asm volatile("s_waitcnt lgkmcnt(0)" ::: "memory");
    __builtin_amdgcn_sched_barrier(0);
    MFMA_QUAD(1, 1, a, b1);
    MFMA_QUAD(1, 0, a, b0);
  }
#undef MFMA_QUAD
}

// ---------------- QKV projection GEMM (256x256 tile, 512 threads) ------------------------
// n0 < 2048: Q/K, normal orientation, coalesced (bh,s,d) stores.
// n0 >= 2048: V, transposed accumulator, DIRECT V^T (bh,d,s) stores.
// 256-tiles never straddle the Q/K/V boundaries (1024 & 2048 are multiples of 256).
__global__ __launch_bounds__(512, 2) void qkv_gemm_kernel(const unsigned short* __restrict__ Xb,
                                                          const unsigned short* __restrict__ Wt,
                                                          const float* __restrict__ bias,
                                                          unsigned short* __restrict__ Qw,
                                                          unsigned short* __restrict__ Kw,
                                                          unsigned short* __restrict__ Vtw) {
  __shared__ __align__(16) unsigned short sA[2 * 2 * 8192];   // 64 KB (dbuf x mh-slice)
  __shared__ __align__(16) unsigned short sB[2 * 2 * 8192];   // 64 KB (dbuf x nh-slice)
  f32x4 acc[8][4];
  const int m0 = blockIdx.y * 256, n0 = blockIdx.x * 256;
  const int t = threadIdx.x, lane = t & 63, wave = t >> 6;
  const int wr = wave >> 2, wc = wave & 3, lhi = lane >> 4, llo = lane & 15;

  if (n0 < 2048) {
    gemm_mainloop_256q<false>(Xb, Wt, m0, n0, sA, sB, acc);
    const int c = n0 >> 10;     // block-uniform: Q or K
    unsigned short* __restrict__ Dst = (c == 0) ? Qw : Kw;
    const float qs = (c == 0) ? 0.125f : 1.0f;
#pragma unroll
    for (int mi = 0; mi < 8; ++mi) {
#pragma unroll
      for (int nj = 0; nj < 4; ++nj) {
        int n = n0 + wc * 64 + nj * 16 + llo;
        float bv = bias[n];
        int h = (n >> 6) & 15, d = n & 63;
#pragma unroll
        for (int r = 0; r < 4; ++r) {
          int m = m0 + wr * 128 + mi * 16 + lhi * 4 + r;
          int b = m >> 11, s = m & 2047;
          int bh = b * 16 + h;
          Dst[((size_t)(bh * 2048 + s)) * 64 + d] = f2bf((acc[mi][nj][r] + bv) * qs);
        }
      }
    }
  } else {
    gemm_mainloop_256q<true>(Xb, Wt, m0, n0, sA, sB, acc);
#pragma unroll
    for (int mi = 0; mi < 8; ++mi) {
      int m = m0 + wr * 128 + mi * 16 + llo;   // s-dim (col of C^T)
      int b = m >> 11, s = m & 2047;
#pragma unroll
      for (int nj = 0; nj < 4; ++nj) {
        int nb = n0 + wc * 64 + nj * 16 + lhi * 4;   // d-base (row of C^T), 4-aligned
        float4 bv = *(const float4*)(bias + nb);
        int h = (nb >> 6) & 15, dbase = nb & 63;
        int bh = b * 16 + h;
        float bvr[4] = {bv.x, bv.y, bv.z, bv.w};
#pragma unroll
        for (int r = 0; r < 4; ++r)
          Vtw[(size_t)(bh * 64 + dbase + r) * 2048 + s] = f2bf(acc[mi][nj][r] + bvr[r]);
      }
    }
  }
}

// ---------------- flash sliding-window attention (S^T, 512 threads, 3-stage K/V) ---------
__global__ __launch_bounds__(512) void attn_kernel(const unsigned short* __restrict__ Qw,
                                                   const unsigned short* __restrict__ Kw,
                                                   const unsigned short* __restrict__ Vtw,
                                                   unsigned short* __restrict__ AO) {
  __shared__ __align__(16) unsigned short sK[3][64 * 64];  // (key,d), XOR-swizzled chunks
  __shared__ __align__(16) unsigned short sV[3][64 * 64];  // (d,key), XOR-swizzled chunks
  __shared__ __align__(16) unsigned short sP[8][16 * 72];  // per-wave P (query,key), pad 72
  const int t = threadIdx.x, lane = t & 63, wave = t >> 6;  // wave 0..7
  const int lhi = lane >> 4, llo = lane & 15;
  const int bh = blockIdx.x;                 // bh%8 -> XCD; q-tiles of bh share L2
  const int q0 = (15 - blockIdx.y) << 7;     // heaviest q-tiles dispatch first
  const unsigned short* Qb = Qw  + (size_t)bh * 2048 * 64;
  const unsigned short* Kb = Kw  + (size_t)bh * 2048 * 64;
  const unsigned short* Vb = Vtw + (size_t)bh * 64 * 2048;

  const int qw = q0 + wave * 16;             // this wave's query base
  const int qrow = qw + llo;                 // this lane's query (column of S^T)
  bf16x8 qf0 = *(const bf16x8*)(Qb + (size_t)qrow * 64 + lhi * 8);
  bf16x8 qf1 = *(const bf16x8*)(Qb + (size_t)qrow * 64 + 32 + lhi * 8);

  const int srow = t >> 3;                   // 512 threads cover a full 64x64 bf16 tile
  const int scol = ((t & 7) ^ (srow & 7)) * 8;   // XOR-swizzled staging chunk
  const int cpos  = (lhi ^ (llo & 7)) * 8;       // swizzled chunk for frag reads
  const int cposx = cpos ^ 32;                   // chunk c^4

  float m_i = -1e30f, l_i = 0.f;
  f32x4 o[4];
  f32x4 zero = {0.f, 0.f, 0.f, 0.f};
#pragma unroll
  for (int td = 0; td < 4; ++td) o[td] = zero;

  const int kt_lo = (q0 > 511) ? ((q0 - 511) >> 6) : 0;
  const int kt_hi = (q0 + 127) >> 6;         // every block has >= 2 k-tiles

  auto stageKV = [&](int j) {
    const int k0 = j << 6;
    unsigned short* dK = sK[j % 3];
    unsigned short* dV = sV[j % 3];
    gld16(Kb + (size_t)(k0 + srow) * 64 + scol, dK + t * 8);
    gld16(Vb + (size_t)srow * 2048 + k0 + scol, dV + t * 8);
  };

  stageKV(kt_lo);
  stageKV(kt_lo + 1);

  for (int kt = kt_lo; kt <= kt_hi; ++kt) {
    // wait for tile kt (2 oldest); keep tile kt+1 (2 newest) in flight across barrier
    if (kt < kt_hi) asm volatile("s_waitcnt vmcnt(2)\n\ts_barrier" ::: "memory");
    else            asm volatile("s_waitcnt vmcnt(0)\n\ts_barrier" ::: "memory");
    if (kt + 2 <= kt_hi) stageKV(kt + 2);
    const int k0 = kt << 6;
    // per-wave uniform skip: wave queries qw..qw+15, window union [qw-511, qw+15]
    if (k0 > qw + 15 || k0 + 63 < qw - (WINDOW - 1)) continue;  // no barrier inside

    const unsigned short* bK = sK[kt % 3];
    const unsigned short* bV = sV[kt % 3];

    // S^T tiles: row = key (tk*16 + lhi*4 + r), col = query (llo)
    f32x4 st[4];
#pragma unroll
    for (int tk = 0; tk < 4; ++tk) {
      const unsigned short* kr = bK + (tk * 16 + llo) * 64;
      bf16x8 kf0 = *(const bf16x8*)(kr + cpos);
      bf16x8 kf1 = *(const bf16x8*)(kr + cposx);
      f32x4 z = zero;
      z = mfma16(kf0, qf0, z);
      z = mfma16(kf1, qf1, z);
      st[tk] = z;
    }

    // wave-uniform interior fast path: all 16 keysx queries valid -> skip masking
    const bool interior = (k0 >= qw - (WINDOW - 1 - 15)) && (k0 + 63 <= qw);
    const int kb = k0 + lhi * 4;
    float mx = -1e30f;
    if (interior) {
#pragma unroll
      for (int tk = 0; tk < 4; ++tk)
#pragma unroll
        for (int r = 0; r < 4; ++r) mx = fmaxf(mx, st[tk][r]);
    } else {
#pragma unroll
      for (int tk = 0; tk < 4; ++tk)
#pragma unroll
        for (int r = 0; r < 4; ++r) {
          int key = kb + tk * 16 + r;
          bool ok = (key <= qrow) && (qrow - key < WINDOW);
          float s = ok ? st[tk][r] : -1e30f;
          st[tk][r] = s;
          mx = fmaxf(mx, s);
        }
    }
    mx = fmaxf(mx, __shfl_xor(mx, 16));
    mx = fmaxf(mx, __shfl_xor(mx, 32));
    float mn = fmaxf(m_i, mx);
    float a  = __expf(m_i - mn);  // fully-masked tile garbage wiped by a=0 on next real tile
    float rs = 0.f;
    unsigned short* pw = &sP[wave][llo * 72];
#pragma unroll
    for (int tk = 0; tk < 4; ++tk) {
      ushort4 pb;
      pb.x = f2bf(__expf(st[tk][0] - mn));
      pb.y = f2bf(__expf(st[tk][1] - mn));
      pb.z = f2bf(__expf(st[tk][2] - mn));
      pb.w = f2bf(__expf(st[tk][3] - mn));
      *(ushort4*)(pw + tk * 16 + lhi * 4) = pb;
      rs += bf2f(pb.x) + bf2f(pb.y) + bf2f(pb.z) + bf2f(pb.w);
    }
    rs += __shfl_xor(rs, 16);
    rs += __shfl_xor(rs, 32);
    l_i = l_i * a + rs;
    m_i = mn;

    float aR[4];
#pragma unroll
    for (int r = 0; r < 4; ++r) aR[r] = __shfl(a, lhi * 4 + r);
#pragma unroll
    for (int td = 0; td < 4; ++td)
#pragma unroll
      for (int r = 0; r < 4; ++r) o[td][r] *= aR[r];

    // O += P V (same-wave LDS write->read ordering, no barrier needed)
    bf16x8 pf0 = *(const bf16x8*)(pw + lhi * 8);
    bf16x8 pf1 = *(const bf16x8*)(pw + 32 + lhi * 8);
#pragma unroll
    for (int td = 0; td < 4; ++td) {
      const unsigned short* vr = bV + (td * 16 + llo) * 64;
      bf16x8 vf0 = *(const bf16x8*)(vr + cpos);
      bf16x8 vf1 = *(const bf16x8*)(vr + cposx);
      o[td] = mfma16(pf0, vf0, o[td]);
      o[td] = mfma16(pf1, vf1, o[td]);
    }
  }

  float lR[4];
#pragma unroll
  for (int r = 0; r < 4; ++r) lR[r] = 1.f / __shfl(l_i, lhi * 4 + r);
  const int b = bh >> 4, h = bh & 15;
#pragma unroll
  for (int td = 0; td < 4; ++td)
#pragma unroll
    for (int r = 0; r < 4; ++r) {
      int qr = q0 + wave * 16 + lhi * 4 + r;
      AO[(size_t)(b * 2048 + qr) * 1024 + h * 64 + td * 16 + llo] = f2bf(o[td][r] * lR[r]);
    }
}

// ---------------- output projection GEMM (128x128 tile, 512 threads) ---------------------
__global__ __launch_bounds__(512, 2) void out_gemm_kernel(const unsigned short* __restrict__ AO,
                                                          const unsigned short* __restrict__ Wt,
                                                          const float* __restrict__ bias,
                                                          float* __restrict__ out) {
  __shared__ __align__(16) unsigned short sA[3][128 * 32];
  __shared__ __align__(16) unsigned short sB[3][128 * 32];
  f32x4 acc[2][4];
  const int m0 = blockIdx.y * 128, n0 = blockIdx.x * 128;
  gemm_mainloop512<false, D_MODEL>(AO, Wt, m0, n0, sA[0], sB[0], acc);

  const int t = threadIdx.x, lane = t & 63, wave = t >> 6;
  const int wr = wave >> 1, wc = wave & 1, lhi = lane >> 4, llo = lane & 15;
#pragma unroll
  for (int ti = 0; ti < 2; ++ti)
#pragma unroll
    for (int tj = 0; tj < 4; ++tj) {
      int n = n0 + wc * 64 + tj * 16 + llo;
      float bv = bias[n];
#pragma unroll
      for (int r = 0; r < 4; ++r) {
        int m = m0 + wr * 32 + ti * 16 + lhi * 4 + r;
        out[(size_t)m * D_MODEL + n] = acc[ti][tj][r] + bv;
      }
    }
}

extern "C" void kernel_launch(void* const* d_in, const int* in_sizes, int n_in,
                              void* d_out, int out_size, void* d_ws, size_t ws_size,
                              hipStream_t stream) {
  const float* x      = (const float*)d_in[0];
  const float* qkv_w  = (const float*)d_in[1];
  const float* qkv_b  = (const float*)d_in[2];
  const float* out_w  = (const float*)d_in[3];
  const float* out_b  = (const float*)d_in[4];
  float* out = (float*)d_out;
  char* ws = (char*)d_ws;

  // workspace layout (48 MB total)
  unsigned short* Xb  = (unsigned short*)(ws);                          // 8 MB  x bf16
  unsigned short* Wq  = (unsigned short*)(ws + ((size_t)8  << 20));     // 6 MB  qkv_w^T bf16
  unsigned short* Wo  = (unsigned short*)(ws + ((size_t)14 << 20));     // 2 MB  out_w^T bf16
  unsigned short* Qw  = (unsigned short*)(ws + ((size_t)16 << 20));     // 8 MB  Q (bh,s,d)*1/8
  unsigned short* Kw  = (unsigned short*)(ws + ((size_t)24 << 20));     // 8 MB  K (bh,s,d)
  unsigned short* Vtw = (unsigned short*)(ws + ((size_t)32 << 20));     // 8 MB  V^T (bh,d,s)
  unsigned short* AO  = (unsigned short*)(ws + ((size_t)40 << 20));     // 8 MB  attn out (m,hd)

  prep_kernel<<<8192, 256, 0, stream>>>(x, qkv_w, out_w, Xb, Wq, Wo);
  qkv_gemm_kernel<<<dim3(NQKV / 256, MTOT / 256), 512, 0, stream>>>(Xb, Wq, qkv_b, Qw, Kw, Vtw);
  attn_kernel<<<dim3(BATCH * NUM_HEADS, SEQ / 128), 512, 0, stream>>>(Qw, Kw, Vtw, AO);
  out_gemm_kernel<<<dim3(D_MODEL / 128, MTOT / 128), 512, 0, stream>>>(AO, Wo, out_b, out);
}